// Round 6
// baseline (391.971 us; speedup 1.0000x reference)
//
#include <hip/hip_runtime.h>
#include <hip/hip_bf16.h>
#include <math.h>

typedef __attribute__((ext_vector_type(8))) short bf8;
typedef __attribute__((ext_vector_type(4))) float f4;

typedef const __attribute__((address_space(1))) void* gas_t;
typedef __attribute__((address_space(3))) void* las_t;

__device__ __forceinline__ ushort f2bf(float x){
  union { float f; unsigned u; } v; v.f = x;
  unsigned r = (v.u + 0x7fffu + ((v.u >> 16) & 1u)) >> 16;
  return (ushort)r;
}
__device__ __forceinline__ float bf2f(ushort b){
  union { unsigned u; float f; } v; v.u = ((unsigned)b) << 16;
  return v.f;
}

// ---------------- 128x128 (or 128x64 dual-B) tile bf16 MFMA GEMM, m97-style ----------------
// global_load_lds width-16 staging: LINEAR LDS dest (wave-uniform base + lane*16),
// XOR-swizzle folded into the per-lane GLOBAL source column. Reader unchanged.
struct GP {
  const ushort* A; long lda; long aBatch;
  const ushort* Bt; long ldb; long bBatch;
  const ushort* Bt2;
  int K;
  float* outf; ushort* outb;
  ushort* o1; ushort* o2; ushort* o3;
  const float* bias0; const float* bias1; const float* bias2; const float* bias3;
  const float* addf;
};

enum { EP_QKVG=0, EP_GCN, EP_ATTNOUT, EP_FF, EP_FINAL };

template<int EPI, bool DUAL, int BN>
__global__ __launch_bounds__(256)
void gemm_k(GP p) {
  constexpr int WMW = (BN==128) ? 2 : 4;           // waves along M
  constexpr int WNW = (BN==128) ? 2 : 1;           // waves along N
  constexpr int WM = 128/WMW, WN = BN/WNW;         // per-wave output
  constexpr int MF = WM/16, NF = WN/16;            // 16x16 fragment repeats
  constexpr int BI = BN/32;                        // B staging iterations
  __shared__ __align__(16) ushort As[128*64];
  __shared__ __align__(16) ushort Bs[BN*64];
  __shared__ __align__(16) ushort Bs2[DUAL ? BN*64 : 8];
  const int tid = threadIdx.x;
  const int lane = tid & 63, w = tid >> 6;
  const int wm = (WNW==1) ? w : (w >> 1);
  const int wn = (WNW==1) ? 0 : (w & 1);
  const int g = lane >> 4, lr = lane & 15;
  const int lr8 = lane >> 3, sc = lane & 7;
  const int bm = blockIdx.x, bn = blockIdx.y, z = blockIdx.z;

  const ushort* Ab  = p.A  + (long)z*p.aBatch + (long)bm*128*p.lda;
  const ushort* Btb = p.Bt + (long)z*p.bBatch + (long)bn*BN*p.ldb;
  const ushort* Bt2b = DUAL ? (p.Bt2 + (long)bn*BN*p.ldb) : (const ushort*)nullptr;

  f4 acc[MF][NF] = {};
  f4 acc2[DUAL?MF:1][DUAL?NF:1] = {};

  for (int k0 = 0; k0 < p.K; k0 += 64) {
    // ---- async global->LDS staging (linear dest, pre-swizzled source) ----
    #pragma unroll
    for (int i = 0; i < 4; ++i) {
      int row = i*32 + w*8 + lr8;
      const ushort* gs = Ab + (long)row*p.lda + k0 + ((sc ^ (row & 7)) << 3);
      __builtin_amdgcn_global_load_lds((gas_t)gs, (las_t)&As[i*2048 + w*512], 16, 0, 0);
    }
    #pragma unroll
    for (int i = 0; i < BI; ++i) {
      int row = i*32 + w*8 + lr8;
      const ushort* gs = Btb + (long)row*p.ldb + k0 + ((sc ^ (row & 7)) << 3);
      __builtin_amdgcn_global_load_lds((gas_t)gs, (las_t)&Bs[i*2048 + w*512], 16, 0, 0);
    }
    if (DUAL) {
      #pragma unroll
      for (int i = 0; i < BI; ++i) {
        int row = i*32 + w*8 + lr8;
        const ushort* gs = Bt2b + (long)row*p.ldb + k0 + ((sc ^ (row & 7)) << 3);
        __builtin_amdgcn_global_load_lds((gas_t)gs, (las_t)&Bs2[i*2048 + w*512], 16, 0, 0);
      }
    }
    __syncthreads();

    // ---- compute ----
    #pragma unroll
    for (int kw = 0; kw < 2; ++kw) {
      const int chunk = kw*4 + g;
      bf8 af[MF], bfr[NF], bf2[DUAL?NF:1];
      #pragma unroll
      for (int f = 0; f < MF; ++f) {
        int ar = wm*WM + f*16 + lr;
        af[f] = *(const bf8*)&As[ar*64 + ((chunk ^ (ar & 7)) << 3)];
      }
      #pragma unroll
      for (int f = 0; f < NF; ++f) {
        int br = wn*WN + f*16 + lr;
        bfr[f] = *(const bf8*)&Bs[br*64 + ((chunk ^ (br & 7)) << 3)];
        if (DUAL) bf2[f] = *(const bf8*)&Bs2[br*64 + ((chunk ^ (br & 7)) << 3)];
      }
      #pragma unroll
      for (int fm = 0; fm < MF; ++fm)
        #pragma unroll
        for (int fn = 0; fn < NF; ++fn) {
          acc[fm][fn] = __builtin_amdgcn_mfma_f32_16x16x32_bf16(af[fm], bfr[fn], acc[fm][fn], 0,0,0);
          if (DUAL) acc2[fm][fn] = __builtin_amdgcn_mfma_f32_16x16x32_bf16(af[fm], bf2[fn], acc2[fm][fn], 0,0,0);
        }
    }
    __syncthreads();
  }

  #pragma unroll
  for (int fm = 0; fm < MF; ++fm)
  #pragma unroll
  for (int fn = 0; fn < NF; ++fn)
  #pragma unroll
  for (int i = 0; i < 4; ++i) {
    int grow = bm*128 + wm*WM + fm*16 + g*4 + i;
    int gcol = bn*BN + wn*WN + fn*16 + lr;
    float v = acc[fm][fn][i];
    if constexpr (EPI == EP_QKVG) {
      int sec = gcol >> 9, cc = gcol & 511;
      const float* bp = sec==0 ? p.bias0 : sec==1 ? p.bias1 : sec==2 ? p.bias2 : p.bias3;
      v += bp[cc];
      ushort bvv = f2bf(v);
      if (sec == 0)      p.outb[(long)grow*512 + cc] = bvv;
      else if (sec == 1) p.o1[(long)grow*512 + cc] = bvv;
      else {
        int b = grow / 768, l = grow - b*768;
        ushort* dst = (sec==2) ? p.o2 : p.o3;
        dst[((long)b*512 + cc)*768 + l] = bvv;
      }
    } else if constexpr (EPI == EP_GCN) {
      float ge = 0.5f * v * (1.f + erff(v * 0.70710678118f));
      p.outf[((long)z*768 + grow)*512 + gcol] = ge;
    } else if constexpr (EPI == EP_ATTNOUT) {
      p.outf[(long)grow*512 + gcol] = v + p.bias0[gcol];
    } else if constexpr (EPI == EP_FF) {
      float u = v + p.bias0[gcol];
      float gt = acc2[fm][fn][i] + p.bias0[2048 + gcol];
      float a = u / (1.f + expf(-gt));
      p.outb[(long)grow*2048 + gcol] = f2bf(a);
    } else if constexpr (EPI == EP_FINAL) {
      long idx = (long)grow*512 + gcol;
      p.outf[idx] = p.addf[idx] + v + p.bias0[gcol];
    }
  }
}

// -------- fused flash attention: scores(+bias) -> online softmax -> PV --------
__global__ __launch_bounds__(256) void flash_k(const ushort* __restrict__ qg,
    const ushort* __restrict__ kg, const ushort* __restrict__ vtg,
    const ushort* __restrict__ biasg, ushort* __restrict__ ctx) {
  __shared__ __align__(16) ushort Ks[64*64];
  __shared__ __align__(16) ushort Vs[64*64];
  __shared__ __align__(16) ushort Ps[64*64];
  const int tid = threadIdx.x;
  const int lane = tid & 63, w = tid >> 6;
  const int g = lane >> 4, lr = lane & 15;
  const int qt = blockIdx.x, bh = blockIdx.y;
  const int b = bh >> 3, h = bh & 7;
  const int q0 = qt*64;

  bf8 aq[2];
  #pragma unroll
  for (int kk = 0; kk < 2; ++kk)
    aq[kk] = *(const bf8*)&qg[(long)(b*768 + q0 + w*16 + lr)*512 + h*64 + kk*32 + g*8];

  f4 o[4] = {};
  float mrow[4], lsum[4];
  #pragma unroll
  for (int i = 0; i < 4; ++i) { mrow[i] = -1e30f; lsum[i] = 0.f; }

  const int srow = tid >> 3, sc = tid & 7;

  for (int kt = 0; kt < 12; ++kt) {
    const int kbase = kt*64;
    #pragma unroll
    for (int ps = 0; ps < 2; ++ps) {
      int r = srow + ps*32;
      int sw = ((sc ^ (r & 7)) * 8);
      *(uint4*)&Ks[r*64 + sw] = *(const uint4*)&kg[(long)(b*768 + kbase + r)*512 + h*64 + sc*8];
      *(uint4*)&Vs[r*64 + sw] = *(const uint4*)&vtg[((long)b*512 + h*64 + r)*768 + kbase + sc*8];
    }
    __syncthreads();

    f4 s[4] = {};
    #pragma unroll
    for (int kn = 0; kn < 4; ++kn) {
      #pragma unroll
      for (int kk = 0; kk < 2; ++kk) {
        int row = kn*16 + lr;
        bf8 bk = *(const bf8*)&Ks[row*64 + (((kk*4+g) ^ (row & 7)) * 8)];
        s[kn] = __builtin_amdgcn_mfma_f32_16x16x32_bf16(aq[kk], bk, s[kn], 0,0,0);
      }
    }

    float pv[4][4];
    #pragma unroll
    for (int kn = 0; kn < 4; ++kn)
      #pragma unroll
      for (int i = 0; i < 4; ++i) {
        float bv = bf2f(biasg[((long)bh*768 + q0 + w*16 + g*4 + i)*768 + kbase + kn*16 + lr]);
        pv[kn][i] = s[kn][i]*0.125f + bv;
      }

    #pragma unroll
    for (int i = 0; i < 4; ++i) {
      float m2 = fmaxf(fmaxf(pv[0][i], pv[1][i]), fmaxf(pv[2][i], pv[3][i]));
      #pragma unroll
      for (int off = 1; off < 16; off <<= 1) m2 = fmaxf(m2, __shfl_xor(m2, off, 64));
      float mnew = fmaxf(mrow[i], m2);
      float scale = __expf(mrow[i] - mnew);
      mrow[i] = mnew;
      float psum = 0.f;
      #pragma unroll
      for (int kn = 0; kn < 4; ++kn) { pv[kn][i] = __expf(pv[kn][i] - mnew); psum += pv[kn][i]; }
      #pragma unroll
      for (int off = 1; off < 16; off <<= 1) psum += __shfl_xor(psum, off, 64);
      lsum[i] = lsum[i]*scale + psum;
      #pragma unroll
      for (int dn = 0; dn < 4; ++dn) o[dn][i] *= scale;
    }

    #pragma unroll
    for (int kn = 0; kn < 4; ++kn)
      #pragma unroll
      for (int i = 0; i < 4; ++i) {
        int row = w*16 + g*4 + i;
        int col = kn*16 + lr;
        Ps[row*64 + (((col >> 3) ^ (row & 7)) * 8) + (col & 7)] = f2bf(pv[kn][i]);
      }

    #pragma unroll
    for (int kk2 = 0; kk2 < 2; ++kk2) {
      int prow = w*16 + lr;
      bf8 pa = *(const bf8*)&Ps[prow*64 + (((kk2*4+g) ^ (prow & 7)) * 8)];
      #pragma unroll
      for (int dn = 0; dn < 4; ++dn) {
        int vrow = dn*16 + lr;
        bf8 bv = *(const bf8*)&Vs[vrow*64 + (((kk2*4+g) ^ (vrow & 7)) * 8)];
        o[dn] = __builtin_amdgcn_mfma_f32_16x16x32_bf16(pa, bv, o[dn], 0,0,0);
      }
    }
    __syncthreads();
  }

  #pragma unroll
  for (int i = 0; i < 4; ++i) {
    float inv = 1.f / lsum[i];
    #pragma unroll
    for (int dn = 0; dn < 4; ++dn)
      ctx[(long)(b*768 + q0 + w*16 + g*4 + i)*512 + h*64 + dn*16 + lr] = f2bf(o[dn][i]*inv);
  }
}

// ---------------- transpose + fp32->bf16 convert ----------------
__global__ __launch_bounds__(256) void transpose_bf(const float* src, ushort* dst, int R, int C) {
  __shared__ float t[32][33];
  int r0 = blockIdx.x*32, c0 = blockIdx.y*32;
  int tr = threadIdx.x >> 5, tc = threadIdx.x & 31;
  #pragma unroll
  for (int i = 0; i < 4; ++i)
    t[tr + i*8][tc] = src[(long)(r0 + tr + i*8)*C + c0 + tc];
  __syncthreads();
  #pragma unroll
  for (int i = 0; i < 4; ++i)
    dst[(long)(c0 + tr + i*8)*R + r0 + tc] = f2bf(t[tc][tr + i*8]);
}

// ---------------- LayerNorm (row=512) -> bf16 ----------------
__global__ __launch_bounds__(256) void ln_k(const float* x, const float* gam, const float* bet, ushort* out) {
  int row = blockIdx.x, tid = threadIdx.x;
  long base = (long)row*512;
  float v0 = x[base+tid], v1 = x[base+tid+256];
  float s = v0+v1, q = v0*v0 + v1*v1;
  #pragma unroll
  for (int off=32; off>=1; off>>=1){ s += __shfl_down(s,off,64); q += __shfl_down(q,off,64); }
  __shared__ float red[8];
  int lane=tid&63, wave=tid>>6;
  if (lane==0){ red[wave]=s; red[4+wave]=q; }
  __syncthreads();
  if (tid==0){ red[0]=red[0]+red[1]+red[2]+red[3]; red[4]=red[4]+red[5]+red[6]+red[7]; }
  __syncthreads();
  float mu = red[0]*(1.f/512.f);
  float var = red[4]*(1.f/512.f) - mu*mu;
  float rs = rsqrtf(var + 1e-5f);
  out[base+tid]     = f2bf((v0-mu)*rs*gam[tid]     + bet[tid]);
  out[base+tid+256] = f2bf((v1-mu)*rs*gam[tid+256] + bet[tid+256]);
}

// ---------------- residual + LayerNorm2 ----------------
__global__ __launch_bounds__(256) void resid_ln2_k(const float* x, const float* ao, const float* gc,
    const float* gatep, const float* gam, const float* bet, float* xmid, ushort* h2) {
  int row = blockIdx.x, tid = threadIdx.x;
  long base = (long)row*512;
  float gate = *gatep;
  float v0 = x[base+tid]     + ao[base+tid]     + gc[base+tid]*gate;
  float v1 = x[base+tid+256] + ao[base+tid+256] + gc[base+tid+256]*gate;
  xmid[base+tid] = v0; xmid[base+tid+256] = v1;
  float s = v0+v1, q = v0*v0 + v1*v1;
  #pragma unroll
  for (int off=32; off>=1; off>>=1){ s += __shfl_down(s,off,64); q += __shfl_down(q,off,64); }
  __shared__ float red[8];
  int lane=tid&63, wave=tid>>6;
  if (lane==0){ red[wave]=s; red[4+wave]=q; }
  __syncthreads();
  if (tid==0){ red[0]=red[0]+red[1]+red[2]+red[3]; red[4]=red[4]+red[5]+red[6]+red[7]; }
  __syncthreads();
  float mu = red[0]*(1.f/512.f);
  float var = red[4]*(1.f/512.f) - mu*mu;
  float rs = rsqrtf(var + 1e-5f);
  h2[base+tid]     = f2bf((v0-mu)*rs*gam[tid]     + bet[tid]);
  h2[base+tid+256] = f2bf((v1-mu)*rs*gam[tid+256] + bet[tid+256]);
}

// ------- fused single geom pass: adj (row-normalized) + 8-head score bias -------
__global__ __launch_bounds__(256) void adjbias_k(const float* __restrict__ geom,
    const int* __restrict__ mask, const float* __restrict__ Wg, const float* __restrict__ bg,
    ushort* __restrict__ adjb, ushort* __restrict__ biasb) {
  int bl = blockIdx.x;
  int b = bl / 768, l = bl - b*768;
  int tid = threadIdx.x;
  __shared__ float wgs[56];
  __shared__ float bgs[8];
  if (tid < 56) wgs[tid] = Wg[tid];
  if (tid < 8)  bgs[tid] = bg[tid];
  __syncthreads();
  float ml = (float)mask[bl];
  float e[3]; float ssum = 0.f;
  #pragma unroll
  for (int j = 0; j < 3; ++j) {
    int m = tid + j*256;
    const float* gp = &geom[((long)bl*768 + m)*7];
    float g0 = gp[0], g1 = gp[1], g2 = gp[2], g3 = gp[3], g4 = gp[4], g5 = gp[5], g6 = gp[6];
    float mm = (float)mask[b*768 + m];
    e[j] = __expf(-g0*0.2f) * mm;
    ssum += e[j];
    #pragma unroll
    for (int hh = 0; hh < 8; ++hh) {
      float bv = bgs[hh] + g0*wgs[hh] + g1*wgs[8+hh] + g2*wgs[16+hh] + g3*wgs[24+hh]
               + g4*wgs[32+hh] + g5*wgs[40+hh] + g6*wgs[48+hh];
      biasb[((long)(b*8+hh)*768 + l)*768 + m] = f2bf(mm != 0.f ? bv : -10000.f);
    }
  }
  #pragma unroll
  for (int off=32; off>=1; off>>=1) ssum += __shfl_down(ssum, off, 64);
  __shared__ float red[4];
  int lane = tid & 63, wave = tid >> 6;
  if (lane == 0) red[wave] = ssum;
  __syncthreads();
  if (tid == 0) red[0] = red[0]+red[1]+red[2]+red[3];
  __syncthreads();
  float inv = ml / (ml*red[0] + 1e-6f);
  #pragma unroll
  for (int j = 0; j < 3; ++j)
    adjb[(long)bl*768 + tid + j*256] = f2bf(e[j] * inv);
}

extern "C" void kernel_launch(void* const* d_in, const int* in_sizes, int n_in,
                              void* d_out, int out_size, void* d_ws, size_t ws_size,
                              hipStream_t stream) {
  const float* x    = (const float*)d_in[0];
  const float* geom = (const float*)d_in[1];
  const int*   mask = (const int*)d_in[2];
  const float* Wq   = (const float*)d_in[3];
  const float* bq   = (const float*)d_in[4];
  const float* Wk   = (const float*)d_in[5];
  const float* bk   = (const float*)d_in[6];
  const float* Wv   = (const float*)d_in[7];
  const float* bv   = (const float*)d_in[8];
  const float* Wo   = (const float*)d_in[9];
  const float* bo   = (const float*)d_in[10];
  const float* Wg   = (const float*)d_in[11];
  const float* bg   = (const float*)d_in[12];
  const float* Wgcn = (const float*)d_in[13];
  const float* bgcn = (const float*)d_in[14];
  const float* gate = (const float*)d_in[15];
  const float* W1   = (const float*)d_in[16];
  const float* b1   = (const float*)d_in[17];
  const float* W2   = (const float*)d_in[18];
  const float* b2   = (const float*)d_in[19];
  const float* ln1s = (const float*)d_in[20];
  const float* ln1b = (const float*)d_in[21];
  const float* ln2s = (const float*)d_in[22];
  const float* ln2b = (const float*)d_in[23];
  float* out = (float*)d_out;

  char* wp = (char*)d_ws;
  auto alloc = [&](size_t bytes)->char* { char* r = wp; wp += (bytes + 255) & ~(size_t)255; return r; };
  ushort* wqkvgT = (ushort*)alloc(2048*512*2);
  ushort* woT    = (ushort*)alloc(512*512*2);
  ushort* w1T    = (ushort*)alloc(4096*512*2);
  ushort* w2T    = (ushort*)alloc(512*2048*2);
  ushort* hbf    = (ushort*)alloc(3072*512*2);
  ushort* qbf    = (ushort*)alloc(3072*512*2);
  ushort* kbf    = (ushort*)alloc(3072*512*2);
  ushort* vt     = (ushort*)alloc((size_t)4*512*768*2);
  ushort* gt     = (ushort*)alloc((size_t)4*512*768*2);
  ushort* adjb   = (ushort*)alloc((size_t)4*768*768*2);
  ushort* biasb  = (ushort*)alloc((size_t)32*768*768*2);
  ushort* ctx    = (ushort*)alloc(3072*512*2);
  float*  aout   = (float*)alloc(3072*512*4);
  float*  gcnr   = (float*)alloc(3072*512*4);
  float*  xmid   = (float*)alloc(3072*512*4);
  ushort* h2bf   = (ushort*)alloc(3072*512*2);
  ushort* act    = biasb;   // reuse: bias dead after flash_k

  transpose_bf<<<dim3(16,16), 256, 0, stream>>>(Wq,   wqkvgT + 0*512*512, 512, 512);
  transpose_bf<<<dim3(16,16), 256, 0, stream>>>(Wk,   wqkvgT + 1*512*512, 512, 512);
  transpose_bf<<<dim3(16,16), 256, 0, stream>>>(Wv,   wqkvgT + 2*512*512, 512, 512);
  transpose_bf<<<dim3(16,16), 256, 0, stream>>>(Wgcn, wqkvgT + 3*512*512, 512, 512);
  transpose_bf<<<dim3(16,16), 256, 0, stream>>>(Wo,   woT, 512, 512);
  transpose_bf<<<dim3(16,128),256, 0, stream>>>(W1,   w1T, 512, 4096);
  transpose_bf<<<dim3(64,16), 256, 0, stream>>>(W2,   w2T, 2048, 512);

  ln_k<<<3072, 256, 0, stream>>>(x, ln1s, ln1b, hbf);
  adjbias_k<<<3072, 256, 0, stream>>>(geom, mask, Wg, bg, adjb, biasb);

  GP p{};
  // QKVG: h @ [Wq|Wk|Wv|Wgcn]  (M=3072,N=2048,K=512)
  p.A = hbf; p.lda = 512; p.aBatch = 0;
  p.Bt = wqkvgT; p.ldb = 512; p.bBatch = 0;
  p.K = 512;
  p.outb = qbf; p.o1 = kbf; p.o2 = vt; p.o3 = gt;
  p.bias0 = bq; p.bias1 = bk; p.bias2 = bv; p.bias3 = bgcn;
  gemm_k<EP_QKVG,false,128><<<dim3(24,16,1), 256, 0, stream>>>(p);

  // flash attention
  flash_k<<<dim3(12,32), 256, 0, stream>>>(qbf, kbf, vt, biasb, ctx);

  // GCN: adj @ g with gelu (M=768,N=512,K=768 per batch)
  p = GP{};
  p.A = adjb; p.lda = 768; p.aBatch = (long)768*768;
  p.Bt = gt; p.ldb = 768; p.bBatch = (long)512*768;
  p.K = 768;
  p.outf = gcnr;
  gemm_k<EP_GCN,false,128><<<dim3(6,4,4), 256, 0, stream>>>(p);

  // attn_out = ctx @ Wo + bo  (M=3072,N=512,K=512)
  p = GP{};
  p.A = ctx; p.lda = 512; p.aBatch = 0;
  p.Bt = woT; p.ldb = 512; p.bBatch = 0;
  p.K = 512;
  p.outf = aout; p.bias0 = bo;
  gemm_k<EP_ATTNOUT,false,128><<<dim3(24,4,1), 256, 0, stream>>>(p);

  resid_ln2_k<<<3072, 256, 0, stream>>>(x, aout, gcnr, gate, ln2s, ln2b, xmid, h2bf);

  // FFN1 dual: u,gate + GLU  (M=3072,N=2048(x2),K=512), BN=64 dual-B
  p = GP{};
  p.A = h2bf; p.lda = 512; p.aBatch = 0;
  p.Bt = w1T; p.ldb = 512; p.bBatch = 0;
  p.Bt2 = w1T + (long)2048*512;
  p.K = 512;
  p.outb = act; p.bias0 = b1;
  gemm_k<EP_FF,true,64><<<dim3(24,32,1), 256, 0, stream>>>(p);

  // FFN2 + final residual  (M=3072,N=512,K=2048)
  p = GP{};
  p.A = act; p.lda = 2048; p.aBatch = 0;
  p.Bt = w2T; p.ldb = 2048; p.bBatch = 0;
  p.K = 2048;
  p.outf = out; p.bias0 = b2; p.addf = xmid;
  gemm_k<EP_FINAL,false,128><<<dim3(24,4,1), 256, 0, stream>>>(p);
}

// Round 8
// 308.955 us; speedup vs baseline: 1.2687x; 1.2687x over previous
//
#include <hip/hip_runtime.h>
#include <hip/hip_bf16.h>
#include <math.h>

typedef __attribute__((ext_vector_type(8))) short bf8;
typedef __attribute__((ext_vector_type(4))) float f4;

typedef const __attribute__((address_space(1))) void* gas_t;
typedef __attribute__((address_space(3))) void* las_t;

__device__ __forceinline__ ushort f2bf(float x){
  union { float f; unsigned u; } v; v.f = x;
  unsigned r = (v.u + 0x7fffu + ((v.u >> 16) & 1u)) >> 16;
  return (ushort)r;
}
__device__ __forceinline__ float bf2f(ushort b){
  union { unsigned u; float f; } v; v.u = ((unsigned)b) << 16;
  return v.f;
}

// ------- 64x64 tile bf16 MFMA GEMM, global_load_lds(16B) staging -------
// LINEAR LDS dest (wave-uniform base + lane*16); XOR swizzle folded into the
// per-lane GLOBAL source column; reader uses the same XOR. (verified r6: absmax ok)
struct GP {
  const ushort* A; long lda; long aBatch;
  const ushort* Bt; long ldb; long bBatch;
  const ushort* Bt2;
  int K;
  float* outf; ushort* outb;
  ushort* o1; ushort* o2; ushort* o3;
  const float* bias0; const float* bias1; const float* bias2; const float* bias3;
  const float* addf;
};

enum { EP_QKVG=0, EP_GCN, EP_ATTNOUT, EP_FF, EP_FINAL };

template<int EPI, bool DUAL>
__global__ __launch_bounds__(256)
void gemm_k(GP p) {
  __shared__ __align__(16) ushort As[64*64];
  __shared__ __align__(16) ushort Bs[64*64];
  __shared__ __align__(16) ushort Bs2[DUAL ? 64*64 : 8];
  const int tid = threadIdx.x;
  const int lane = tid & 63, w = tid >> 6;
  const int wm = w >> 1, wn = w & 1;
  const int g = lane >> 4, lr = lane & 15;
  const int lr8 = lane >> 3, sc = lane & 7;
  const int bm = blockIdx.x, bn = blockIdx.y, z = blockIdx.z;

  const ushort* Ab  = p.A  + (long)z*p.aBatch + (long)bm*64*p.lda;
  const ushort* Btb = p.Bt + (long)z*p.bBatch + (long)bn*64*p.ldb;
  const ushort* Bt2b = DUAL ? (p.Bt2 + (long)bn*64*p.ldb) : (const ushort*)nullptr;

  f4 acc[2][2] = {};
  f4 acc2[DUAL?2:1][DUAL?2:1] = {};

  for (int k0 = 0; k0 < p.K; k0 += 64) {
    // async global->LDS staging: per i, rows i*32 + w*8 + (lane>>3)
    #pragma unroll
    for (int i = 0; i < 2; ++i) {
      int row = i*32 + w*8 + lr8;
      const ushort* gsA = Ab + (long)row*p.lda + k0 + ((sc ^ (row & 7)) << 3);
      __builtin_amdgcn_global_load_lds((gas_t)gsA, (las_t)&As[(i*32 + w*8)*64], 16, 0, 0);
      const ushort* gsB = Btb + (long)row*p.ldb + k0 + ((sc ^ (row & 7)) << 3);
      __builtin_amdgcn_global_load_lds((gas_t)gsB, (las_t)&Bs[(i*32 + w*8)*64], 16, 0, 0);
      if (DUAL) {
        const ushort* gsB2 = Bt2b + (long)row*p.ldb + k0 + ((sc ^ (row & 7)) << 3);
        __builtin_amdgcn_global_load_lds((gas_t)gsB2, (las_t)&Bs2[(i*32 + w*8)*64], 16, 0, 0);
      }
    }
    __syncthreads();

    #pragma unroll
    for (int kw = 0; kw < 2; ++kw) {
      const int chunk = kw*4 + g;
      bf8 af[2], bfr[2], bf2[2];
      #pragma unroll
      for (int f = 0; f < 2; ++f) {
        int ar = wm*32 + f*16 + lr;
        af[f]  = *(const bf8*)&As[ar*64 + ((chunk ^ (ar & 7)) << 3)];
        int br = wn*32 + f*16 + lr;
        bfr[f] = *(const bf8*)&Bs[br*64 + ((chunk ^ (br & 7)) << 3)];
        if (DUAL) bf2[f] = *(const bf8*)&Bs2[br*64 + ((chunk ^ (br & 7)) << 3)];
      }
      #pragma unroll
      for (int fm = 0; fm < 2; ++fm)
        #pragma unroll
        for (int fn = 0; fn < 2; ++fn) {
          acc[fm][fn] = __builtin_amdgcn_mfma_f32_16x16x32_bf16(af[fm], bfr[fn], acc[fm][fn], 0,0,0);
          if (DUAL) acc2[fm][fn] = __builtin_amdgcn_mfma_f32_16x16x32_bf16(af[fm], bf2[fn], acc2[fm][fn], 0,0,0);
        }
    }
    __syncthreads();
  }

  #pragma unroll
  for (int fm = 0; fm < 2; ++fm)
  #pragma unroll
  for (int fn = 0; fn < 2; ++fn)
  #pragma unroll
  for (int i = 0; i < 4; ++i) {
    int grow = bm*64 + wm*32 + fm*16 + g*4 + i;
    int gcol = bn*64 + wn*32 + fn*16 + lr;
    float v = acc[fm][fn][i];
    if constexpr (EPI == EP_QKVG) {
      int sec = gcol >> 9, cc = gcol & 511;
      const float* bp = sec==0 ? p.bias0 : sec==1 ? p.bias1 : sec==2 ? p.bias2 : p.bias3;
      v += bp[cc];
      ushort bvv = f2bf(v);
      if (sec == 0)      p.outb[(long)grow*512 + cc] = bvv;
      else if (sec == 1) p.o1[(long)grow*512 + cc] = bvv;
      else {
        int b = grow / 768, l = grow - b*768;
        ushort* dst = (sec==2) ? p.o2 : p.o3;
        dst[((long)b*512 + cc)*768 + l] = bvv;
      }
    } else if constexpr (EPI == EP_GCN) {
      float ge = 0.5f * v * (1.f + erff(v * 0.70710678118f));
      p.outf[((long)z*768 + grow)*512 + gcol] = ge;
    } else if constexpr (EPI == EP_ATTNOUT) {
      p.outf[(long)grow*512 + gcol] = v + p.bias0[gcol];
    } else if constexpr (EPI == EP_FF) {
      float u = v + p.bias0[gcol];
      float gt = acc2[fm][fn][i] + p.bias0[2048 + gcol];
      float a = u / (1.f + expf(-gt));
      p.outb[(long)grow*2048 + gcol] = f2bf(a);
    } else if constexpr (EPI == EP_FINAL) {
      long idx = (long)grow*512 + gcol;
      p.outf[idx] = p.addf[idx] + v + p.bias0[gcol];
    }
  }
}

// -------- fused flash attention: scores(+bias) -> online softmax -> PV --------
__global__ __launch_bounds__(256) void flash_k(const ushort* __restrict__ qg,
    const ushort* __restrict__ kg, const ushort* __restrict__ vtg,
    const ushort* __restrict__ biasg, ushort* __restrict__ ctx) {
  __shared__ __align__(16) ushort Ks[64*64];
  __shared__ __align__(16) ushort Vs[64*64];
  __shared__ __align__(16) ushort Ps[64*64];
  const int tid = threadIdx.x;
  const int lane = tid & 63, w = tid >> 6;
  const int g = lane >> 4, lr = lane & 15;
  const int qt = blockIdx.x, bh = blockIdx.y;
  const int b = bh >> 3, h = bh & 7;
  const int q0 = qt*64;

  bf8 aq[2];
  #pragma unroll
  for (int kk = 0; kk < 2; ++kk)
    aq[kk] = *(const bf8*)&qg[(long)(b*768 + q0 + w*16 + lr)*512 + h*64 + kk*32 + g*8];

  f4 o[4] = {};
  float mrow[4], lsum[4];
  #pragma unroll
  for (int i = 0; i < 4; ++i) { mrow[i] = -1e30f; lsum[i] = 0.f; }

  const int srow = tid >> 3, sc = tid & 7;

  for (int kt = 0; kt < 12; ++kt) {
    const int kbase = kt*64;
    #pragma unroll
    for (int ps = 0; ps < 2; ++ps) {
      int r = srow + ps*32;
      int sw = ((sc ^ (r & 7)) * 8);
      *(uint4*)&Ks[r*64 + sw] = *(const uint4*)&kg[(long)(b*768 + kbase + r)*512 + h*64 + sc*8];
      *(uint4*)&Vs[r*64 + sw] = *(const uint4*)&vtg[((long)b*512 + h*64 + r)*768 + kbase + sc*8];
    }
    __syncthreads();

    f4 s[4] = {};
    #pragma unroll
    for (int kn = 0; kn < 4; ++kn) {
      #pragma unroll
      for (int kk = 0; kk < 2; ++kk) {
        int row = kn*16 + lr;
        bf8 bk = *(const bf8*)&Ks[row*64 + (((kk*4+g) ^ (row & 7)) * 8)];
        s[kn] = __builtin_amdgcn_mfma_f32_16x16x32_bf16(aq[kk], bk, s[kn], 0,0,0);
      }
    }

    float pv[4][4];
    #pragma unroll
    for (int kn = 0; kn < 4; ++kn)
      #pragma unroll
      for (int i = 0; i < 4; ++i) {
        float bv = bf2f(biasg[((long)bh*768 + q0 + w*16 + g*4 + i)*768 + kbase + kn*16 + lr]);
        pv[kn][i] = s[kn][i]*0.125f + bv;
      }

    #pragma unroll
    for (int i = 0; i < 4; ++i) {
      float m2 = fmaxf(fmaxf(pv[0][i], pv[1][i]), fmaxf(pv[2][i], pv[3][i]));
      #pragma unroll
      for (int off = 1; off < 16; off <<= 1) m2 = fmaxf(m2, __shfl_xor(m2, off, 64));
      float mnew = fmaxf(mrow[i], m2);
      float scale = __expf(mrow[i] - mnew);
      mrow[i] = mnew;
      float psum = 0.f;
      #pragma unroll
      for (int kn = 0; kn < 4; ++kn) { pv[kn][i] = __expf(pv[kn][i] - mnew); psum += pv[kn][i]; }
      #pragma unroll
      for (int off = 1; off < 16; off <<= 1) psum += __shfl_xor(psum, off, 64);
      lsum[i] = lsum[i]*scale + psum;
      #pragma unroll
      for (int dn = 0; dn < 4; ++dn) o[dn][i] *= scale;
    }

    #pragma unroll
    for (int kn = 0; kn < 4; ++kn)
      #pragma unroll
      for (int i = 0; i < 4; ++i) {
        int row = w*16 + g*4 + i;
        int col = kn*16 + lr;
        Ps[row*64 + (((col >> 3) ^ (row & 7)) * 8) + (col & 7)] = f2bf(pv[kn][i]);
      }

    #pragma unroll
    for (int kk2 = 0; kk2 < 2; ++kk2) {
      int prow = w*16 + lr;
      bf8 pa = *(const bf8*)&Ps[prow*64 + (((kk2*4+g) ^ (prow & 7)) * 8)];
      #pragma unroll
      for (int dn = 0; dn < 4; ++dn) {
        int vrow = dn*16 + lr;
        bf8 bv = *(const bf8*)&Vs[vrow*64 + (((kk2*4+g) ^ (vrow & 7)) * 8)];
        o[dn] = __builtin_amdgcn_mfma_f32_16x16x32_bf16(pa, bv, o[dn], 0,0,0);
      }
    }
    __syncthreads();
  }

  #pragma unroll
  for (int i = 0; i < 4; ++i) {
    float inv = 1.f / lsum[i];
    #pragma unroll
    for (int dn = 0; dn < 4; ++dn)
      ctx[(long)(b*768 + q0 + w*16 + g*4 + i)*512 + h*64 + dn*16 + lr] = f2bf(o[dn][i]*inv);
  }
}

// ---------------- transpose + fp32->bf16 convert ----------------
__global__ __launch_bounds__(256) void transpose_bf(const float* src, ushort* dst, int R, int C) {
  __shared__ float t[32][33];
  int r0 = blockIdx.x*32, c0 = blockIdx.y*32;
  int tr = threadIdx.x >> 5, tc = threadIdx.x & 31;
  #pragma unroll
  for (int i = 0; i < 4; ++i)
    t[tr + i*8][tc] = src[(long)(r0 + tr + i*8)*C + c0 + tc];
  __syncthreads();
  #pragma unroll
  for (int i = 0; i < 4; ++i)
    dst[(long)(c0 + tr + i*8)*R + r0 + tc] = f2bf(t[tc][tr + i*8]);
}

// ---------------- LayerNorm (row=512) -> bf16 ----------------
__global__ __launch_bounds__(256) void ln_k(const float* x, const float* gam, const float* bet, ushort* out) {
  int row = blockIdx.x, tid = threadIdx.x;
  long base = (long)row*512;
  float v0 = x[base+tid], v1 = x[base+tid+256];
  float s = v0+v1, q = v0*v0 + v1*v1;
  #pragma unroll
  for (int off=32; off>=1; off>>=1){ s += __shfl_down(s,off,64); q += __shfl_down(q,off,64); }
  __shared__ float red[8];
  int lane=tid&63, wave=tid>>6;
  if (lane==0){ red[wave]=s; red[4+wave]=q; }
  __syncthreads();
  if (tid==0){ red[0]=red[0]+red[1]+red[2]+red[3]; red[4]=red[4]+red[5]+red[6]+red[7]; }
  __syncthreads();
  float mu = red[0]*(1.f/512.f);
  float var = red[4]*(1.f/512.f) - mu*mu;
  float rs = rsqrtf(var + 1e-5f);
  out[base+tid]     = f2bf((v0-mu)*rs*gam[tid]     + bet[tid]);
  out[base+tid+256] = f2bf((v1-mu)*rs*gam[tid+256] + bet[tid+256]);
}

// ---------------- residual + LayerNorm2 ----------------
__global__ __launch_bounds__(256) void resid_ln2_k(const float* x, const float* ao, const float* gc,
    const float* gatep, const float* gam, const float* bet, float* xmid, ushort* h2) {
  int row = blockIdx.x, tid = threadIdx.x;
  long base = (long)row*512;
  float gate = *gatep;
  float v0 = x[base+tid]     + ao[base+tid]     + gc[base+tid]*gate;
  float v1 = x[base+tid+256] + ao[base+tid+256] + gc[base+tid+256]*gate;
  xmid[base+tid] = v0; xmid[base+tid+256] = v1;
  float s = v0+v1, q = v0*v0 + v1*v1;
  #pragma unroll
  for (int off=32; off>=1; off>>=1){ s += __shfl_down(s,off,64); q += __shfl_down(q,off,64); }
  __shared__ float red[8];
  int lane=tid&63, wave=tid>>6;
  if (lane==0){ red[wave]=s; red[4+wave]=q; }
  __syncthreads();
  if (tid==0){ red[0]=red[0]+red[1]+red[2]+red[3]; red[4]=red[4]+red[5]+red[6]+red[7]; }
  __syncthreads();
  float mu = red[0]*(1.f/512.f);
  float var = red[4]*(1.f/512.f) - mu*mu;
  float rs = rsqrtf(var + 1e-5f);
  h2[base+tid]     = f2bf((v0-mu)*rs*gam[tid]     + bet[tid]);
  h2[base+tid+256] = f2bf((v1-mu)*rs*gam[tid+256] + bet[tid+256]);
}

// ------- fused single geom pass: adj (row-normalized) + 8-head score bias -------
__global__ __launch_bounds__(256) void adjbias_k(const float* __restrict__ geom,
    const int* __restrict__ mask, const float* __restrict__ Wg, const float* __restrict__ bg,
    ushort* __restrict__ adjb, ushort* __restrict__ biasb) {
  int bl = blockIdx.x;
  int b = bl / 768, l = bl - b*768;
  int tid = threadIdx.x;
  __shared__ float wgs[56];
  __shared__ float bgs[8];
  if (tid < 56) wgs[tid] = Wg[tid];
  if (tid < 8)  bgs[tid] = bg[tid];
  __syncthreads();
  float ml = (float)mask[bl];
  float e[3]; float ssum = 0.f;
  #pragma unroll
  for (int j = 0; j < 3; ++j) {
    int m = tid + j*256;
    const float* gp = &geom[((long)bl*768 + m)*7];
    float g0 = gp[0], g1 = gp[1], g2 = gp[2], g3 = gp[3], g4 = gp[4], g5 = gp[5], g6 = gp[6];
    float mm = (float)mask[b*768 + m];
    e[j] = __expf(-g0*0.2f) * mm;
    ssum += e[j];
    #pragma unroll
    for (int hh = 0; hh < 8; ++hh) {
      float bv = bgs[hh] + g0*wgs[hh] + g1*wgs[8+hh] + g2*wgs[16+hh] + g3*wgs[24+hh]
               + g4*wgs[32+hh] + g5*wgs[40+hh] + g6*wgs[48+hh];
      biasb[((long)(b*8+hh)*768 + l)*768 + m] = f2bf(mm != 0.f ? bv : -10000.f);
    }
  }
  #pragma unroll
  for (int off=32; off>=1; off>>=1) ssum += __shfl_down(ssum, off, 64);
  __shared__ float red[4];
  int lane = tid & 63, wave = tid >> 6;
  if (lane == 0) red[wave] = ssum;
  __syncthreads();
  if (tid == 0) red[0] = red[0]+red[1]+red[2]+red[3];
  __syncthreads();
  float inv = ml / (ml*red[0] + 1e-6f);
  #pragma unroll
  for (int j = 0; j < 3; ++j)
    adjb[(long)bl*768 + tid + j*256] = f2bf(e[j] * inv);
}

extern "C" void kernel_launch(void* const* d_in, const int* in_sizes, int n_in,
                              void* d_out, int out_size, void* d_ws, size_t ws_size,
                              hipStream_t stream) {
  const float* x    = (const float*)d_in[0];
  const float* geom = (const float*)d_in[1];
  const int*   mask = (const int*)d_in[2];
  const float* Wq   = (const float*)d_in[3];
  const float* bq   = (const float*)d_in[4];
  const float* Wk   = (const float*)d_in[5];
  const float* bk   = (const float*)d_in[6];
  const float* Wv   = (const float*)d_in[7];
  const float* bv   = (const float*)d_in[8];
  const float* Wo   = (const float*)d_in[9];
  const float* bo   = (const float*)d_in[10];
  const float* Wg   = (const float*)d_in[11];
  const float* bg   = (const float*)d_in[12];
  const float* Wgcn = (const float*)d_in[13];
  const float* bgcn = (const float*)d_in[14];
  const float* gate = (const float*)d_in[15];
  const float* W1   = (const float*)d_in[16];
  const float* b1   = (const float*)d_in[17];
  const float* W2   = (const float*)d_in[18];
  const float* b2   = (const float*)d_in[19];
  const float* ln1s = (const float*)d_in[20];
  const float* ln1b = (const float*)d_in[21];
  const float* ln2s = (const float*)d_in[22];
  const float* ln2b = (const float*)d_in[23];
  float* out = (float*)d_out;

  char* wp = (char*)d_ws;
  auto alloc = [&](size_t bytes)->char* { char* r = wp; wp += (bytes + 255) & ~(size_t)255; return r; };
  ushort* wqkvgT = (ushort*)alloc(2048*512*2);
  ushort* woT    = (ushort*)alloc(512*512*2);
  ushort* w1T    = (ushort*)alloc(4096*512*2);
  ushort* w2T    = (ushort*)alloc(512*2048*2);
  ushort* hbf    = (ushort*)alloc(3072*512*2);
  ushort* qbf    = (ushort*)alloc(3072*512*2);
  ushort* kbf    = (ushort*)alloc(3072*512*2);
  ushort* vt     = (ushort*)alloc((size_t)4*512*768*2);
  ushort* gt     = (ushort*)alloc((size_t)4*512*768*2);
  ushort* adjb   = (ushort*)alloc((size_t)4*768*768*2);
  ushort* biasb  = (ushort*)alloc((size_t)32*768*768*2);
  ushort* ctx    = (ushort*)alloc(3072*512*2);
  float*  aout   = (float*)alloc(3072*512*4);
  float*  gcnr   = (float*)alloc(3072*512*4);
  float*  xmid   = (float*)alloc(3072*512*4);
  ushort* h2bf   = (ushort*)alloc(3072*512*2);
  ushort* act    = biasb;   // reuse: bias dead after flash_k

  transpose_bf<<<dim3(16,16), 256, 0, stream>>>(Wq,   wqkvgT + 0*512*512, 512, 512);
  transpose_bf<<<dim3(16,16), 256, 0, stream>>>(Wk,   wqkvgT + 1*512*512, 512, 512);
  transpose_bf<<<dim3(16,16), 256, 0, stream>>>(Wv,   wqkvgT + 2*512*512, 512, 512);
  transpose_bf<<<dim3(16,16), 256, 0, stream>>>(Wgcn, wqkvgT + 3*512*512, 512, 512);
  transpose_bf<<<dim3(16,16), 256, 0, stream>>>(Wo,   woT, 512, 512);
  transpose_bf<<<dim3(16,128),256, 0, stream>>>(W1,   w1T, 512, 4096);
  transpose_bf<<<dim3(64,16), 256, 0, stream>>>(W2,   w2T, 2048, 512);

  ln_k<<<3072, 256, 0, stream>>>(x, ln1s, ln1b, hbf);
  adjbias_k<<<3072, 256, 0, stream>>>(geom, mask, Wg, bg, adjb, biasb);

  GP p{};
  // QKVG: h @ [Wq|Wk|Wv|Wgcn]  (M=3072,N=2048,K=512), grid 48x32=1536 blocks
  p.A = hbf; p.lda = 512; p.aBatch = 0;
  p.Bt = wqkvgT; p.ldb = 512; p.bBatch = 0;
  p.K = 512;
  p.outb = qbf; p.o1 = kbf; p.o2 = vt; p.o3 = gt;
  p.bias0 = bq; p.bias1 = bk; p.bias2 = bv; p.bias3 = bgcn;
  gemm_k<EP_QKVG,false><<<dim3(48,32,1), 256, 0, stream>>>(p);

  // flash attention
  flash_k<<<dim3(12,32), 256, 0, stream>>>(qbf, kbf, vt, biasb, ctx);

  // GCN: adj @ g with gelu (M=768,N=512,K=768 per batch), grid 12x8x4=384
  p = GP{};
  p.A = adjb; p.lda = 768; p.aBatch = (long)768*768;
  p.Bt = gt; p.ldb = 768; p.bBatch = (long)512*768;
  p.K = 768;
  p.outf = gcnr;
  gemm_k<EP_GCN,false><<<dim3(12,8,4), 256, 0, stream>>>(p);

  // attn_out = ctx @ Wo + bo  (M=3072,N=512,K=512), grid 48x8=384
  p = GP{};
  p.A = ctx; p.lda = 512; p.aBatch = 0;
  p.Bt = woT; p.ldb = 512; p.bBatch = 0;
  p.K = 512;
  p.outf = aout; p.bias0 = bo;
  gemm_k<EP_ATTNOUT,false><<<dim3(48,8,1), 256, 0, stream>>>(p);

  resid_ln2_k<<<3072, 256, 0, stream>>>(x, aout, gcnr, gate, ln2s, ln2b, xmid, h2bf);

  // FFN1 dual: u,gate + GLU  (M=3072,N=2048 x2,K=512), grid 48x32=1536
  p = GP{};
  p.A = h2bf; p.lda = 512; p.aBatch = 0;
  p.Bt = w1T; p.ldb = 512; p.bBatch = 0;
  p.Bt2 = w1T + (long)2048*512;
  p.K = 512;
  p.outb = act; p.bias0 = b1;
  gemm_k<EP_FF,true><<<dim3(48,32,1), 256, 0, stream>>>(p);

  // FFN2 + final residual  (M=3072,N=512,K=2048), grid 48x8=384
  p = GP{};
  p.A = act; p.lda = 2048; p.aBatch = 0;
  p.Bt = w2T; p.ldb = 2048; p.bBatch = 0;
  p.K = 2048;
  p.outf = out; p.bias0 = b2; p.addf = xmid;
  gemm_k<EP_FINAL,false><<<dim3(48,8,1), 256, 0, stream>>>(p);
}

// Round 10
// 290.300 us; speedup vs baseline: 1.3502x; 1.0643x over previous
//
#include <hip/hip_runtime.h>
#include <hip/hip_bf16.h>
#include <math.h>

typedef __attribute__((ext_vector_type(8))) short bf8;
typedef __attribute__((ext_vector_type(4))) float f4;

typedef const __attribute__((address_space(1))) void* gas_t;
typedef __attribute__((address_space(3))) void* las_t;

__device__ __forceinline__ ushort f2bf(float x){
  union { float f; unsigned u; } v; v.f = x;
  unsigned r = (v.u + 0x7fffu + ((v.u >> 16) & 1u)) >> 16;
  return (ushort)r;
}
__device__ __forceinline__ float bf2f(ushort b){
  union { unsigned u; float f; } v; v.u = ((unsigned)b) << 16;
  return v.f;
}

// ------- 64x64 tile, BK=128 bf16 MFMA GEMM, global_load_lds(16B) staging -------
// LINEAR LDS dest (wave-uniform base + lane*16B); XOR swizzle (row&15) folded into
// per-lane GLOBAL source column; reader uses same XOR -> <=2-way bank alias (free).
// BK=128: 16 MFMA/wave per barrier pair (2x the BK=64 version) -> half the drains.
struct GP {
  const ushort* A; long lda; long aBatch;
  const ushort* Bt; long ldb; long bBatch;
  const ushort* Bt2;
  int K;
  float* outf; ushort* outb;
  ushort* o1; ushort* o2; ushort* o3;
  const float* bias0; const float* bias1; const float* bias2; const float* bias3;
  const float* addf;
};

enum { EP_QKVG=0, EP_GCN, EP_ATTNOUT, EP_FF, EP_FINAL };

template<int EPI, bool DUAL>
__global__ __launch_bounds__(256)
void gemm_k(GP p) {
  __shared__ __align__(16) ushort As[64*128];
  __shared__ __align__(16) ushort Bs[64*128];
  __shared__ __align__(16) ushort Bs2[DUAL ? 64*128 : 8];
  const int tid = threadIdx.x;
  const int lane = tid & 63, w = tid >> 6;
  const int wm = w >> 1, wn = w & 1;
  const int g = lane >> 4, lr = lane & 15;
  const int cg = lane & 15, rw = lane >> 4;   // staging: col-group, row-within-4
  const int bm = blockIdx.x, bn = blockIdx.y, z = blockIdx.z;

  const ushort* Ab  = p.A  + (long)z*p.aBatch + (long)bm*64*p.lda;
  const ushort* Btb = p.Bt + (long)z*p.bBatch + (long)bn*64*p.ldb;
  const ushort* Bt2b = DUAL ? (p.Bt2 + (long)bn*64*p.ldb) : (const ushort*)nullptr;

  f4 acc[2][2] = {};
  f4 acc2[DUAL?2:1][DUAL?2:1] = {};

  for (int k0 = 0; k0 < p.K; k0 += 128) {
    // staging: instruction i covers rows i*16 + w*4 + rw, col-group cg (8 ushorts)
    #pragma unroll
    for (int i = 0; i < 4; ++i) {
      int row = i*16 + w*4 + rw;
      int scol = (cg ^ (row & 15)) << 3;
      __builtin_amdgcn_global_load_lds((gas_t)(Ab + (long)row*p.lda + k0 + scol),
                                       (las_t)&As[(i*16 + w*4)*128], 16, 0, 0);
      __builtin_amdgcn_global_load_lds((gas_t)(Btb + (long)row*p.ldb + k0 + scol),
                                       (las_t)&Bs[(i*16 + w*4)*128], 16, 0, 0);
      if (DUAL)
        __builtin_amdgcn_global_load_lds((gas_t)(Bt2b + (long)row*p.ldb + k0 + scol),
                                         (las_t)&Bs2[(i*16 + w*4)*128], 16, 0, 0);
    }
    __syncthreads();

    #pragma unroll
    for (int kw = 0; kw < 4; ++kw) {
      const int chunk = kw*4 + g;
      bf8 af[2], bfr[2], bf2[2];
      #pragma unroll
      for (int f = 0; f < 2; ++f) {
        int ar = wm*32 + f*16 + lr;
        af[f]  = *(const bf8*)&As[ar*128 + ((chunk ^ (ar & 15)) << 3)];
        int br = wn*32 + f*16 + lr;
        bfr[f] = *(const bf8*)&Bs[br*128 + ((chunk ^ (br & 15)) << 3)];
        if (DUAL) bf2[f] = *(const bf8*)&Bs2[br*128 + ((chunk ^ (br & 15)) << 3)];
      }
      #pragma unroll
      for (int fm = 0; fm < 2; ++fm)
        #pragma unroll
        for (int fn = 0; fn < 2; ++fn) {
          acc[fm][fn] = __builtin_amdgcn_mfma_f32_16x16x32_bf16(af[fm], bfr[fn], acc[fm][fn], 0,0,0);
          if (DUAL) acc2[fm][fn] = __builtin_amdgcn_mfma_f32_16x16x32_bf16(af[fm], bf2[fn], acc2[fm][fn], 0,0,0);
        }
    }
    __syncthreads();
  }

  #pragma unroll
  for (int fm = 0; fm < 2; ++fm)
  #pragma unroll
  for (int fn = 0; fn < 2; ++fn)
  #pragma unroll
  for (int i = 0; i < 4; ++i) {
    int grow = bm*64 + wm*32 + fm*16 + g*4 + i;
    int gcol = bn*64 + wn*32 + fn*16 + lr;
    float v = acc[fm][fn][i];
    if constexpr (EPI == EP_QKVG) {
      int sec = gcol >> 9, cc = gcol & 511;
      const float* bp = sec==0 ? p.bias0 : sec==1 ? p.bias1 : sec==2 ? p.bias2 : p.bias3;
      v += bp[cc];
      if (sec == 0) v *= 0.125f;          // fold 1/sqrt(dk) into Q
      ushort bvv = f2bf(v);
      if (sec == 0)      p.outb[(long)grow*512 + cc] = bvv;
      else if (sec == 1) p.o1[(long)grow*512 + cc] = bvv;
      else {
        int b = grow / 768, l = grow - b*768;
        ushort* dst = (sec==2) ? p.o2 : p.o3;
        dst[((long)b*512 + cc)*768 + l] = bvv;
      }
    } else if constexpr (EPI == EP_GCN) {
      float ge = 0.5f * v * (1.f + erff(v * 0.70710678118f));
      p.outf[((long)z*768 + grow)*512 + gcol] = ge;
    } else if constexpr (EPI == EP_ATTNOUT) {
      p.outf[(long)grow*512 + gcol] = v + p.bias0[gcol];
    } else if constexpr (EPI == EP_FF) {
      float u = v + p.bias0[gcol];
      float gt = acc2[fm][fn][i] + p.bias0[2048 + gcol];
      float a = u / (1.f + expf(-gt));
      p.outb[(long)grow*2048 + gcol] = f2bf(a);
    } else if constexpr (EPI == EP_FINAL) {
      long idx = (long)grow*512 + gcol;
      p.outf[idx] = p.addf[idx] + v + p.bias0[gcol];
    }
  }
}

// -------- fused flash attention: scores(+bias) -> online softmax -> PV --------
__global__ __launch_bounds__(256) void flash_k(const ushort* __restrict__ qg,
    const ushort* __restrict__ kg, const ushort* __restrict__ vtg,
    const ushort* __restrict__ biasg, ushort* __restrict__ ctx) {
  __shared__ __align__(16) ushort Ks[64*64];
  __shared__ __align__(16) ushort Vs[64*64];
  __shared__ __align__(16) ushort Ps[64*64];
  const int tid = threadIdx.x;
  const int lane = tid & 63, w = tid >> 6;
  const int g = lane >> 4, lr = lane & 15;
  const int qt = blockIdx.x, bh = blockIdx.y;
  const int b = bh >> 3, h = bh & 7;
  const int q0 = qt*64;

  bf8 aq[2];
  #pragma unroll
  for (int kk = 0; kk < 2; ++kk)
    aq[kk] = *(const bf8*)&qg[(long)(b*768 + q0 + w*16 + lr)*512 + h*64 + kk*32 + g*8];

  f4 o[4] = {};
  float mrow[4], lsum[4];
  #pragma unroll
  for (int i = 0; i < 4; ++i) { mrow[i] = -1e30f; lsum[i] = 0.f; }

  const int srow = tid >> 3, sc = tid & 7;

  for (int kt = 0; kt < 12; ++kt) {
    const int kbase = kt*64;
    #pragma unroll
    for (int ps = 0; ps < 2; ++ps) {
      int r = srow + ps*32;
      int sw = ((sc ^ (r & 7)) * 8);
      *(uint4*)&Ks[r*64 + sw] = *(const uint4*)&kg[(long)(b*768 + kbase + r)*512 + h*64 + sc*8];
      *(uint4*)&Vs[r*64 + sw] = *(const uint4*)&vtg[((long)b*512 + h*64 + r)*768 + kbase + sc*8];
    }
    __syncthreads();

    f4 s[4] = {};
    #pragma unroll
    for (int kn = 0; kn < 4; ++kn) {
      #pragma unroll
      for (int kk = 0; kk < 2; ++kk) {
        int row = kn*16 + lr;
        bf8 bk = *(const bf8*)&Ks[row*64 + (((kk*4+g) ^ (row & 7)) * 8)];
        s[kn] = __builtin_amdgcn_mfma_f32_16x16x32_bf16(aq[kk], bk, s[kn], 0,0,0);
      }
    }

    float pv[4][4];
    #pragma unroll
    for (int kn = 0; kn < 4; ++kn)
      #pragma unroll
      for (int i = 0; i < 4; ++i) {
        float bv = bf2f(biasg[((long)bh*768 + q0 + w*16 + g*4 + i)*768 + kbase + kn*16 + lr]);
        pv[kn][i] = s[kn][i] + bv;   // Q pre-scaled by 0.125
      }

    #pragma unroll
    for (int i = 0; i < 4; ++i) {
      float m2 = fmaxf(fmaxf(pv[0][i], pv[1][i]), fmaxf(pv[2][i], pv[3][i]));
      #pragma unroll
      for (int off = 1; off < 16; off <<= 1) m2 = fmaxf(m2, __shfl_xor(m2, off, 64));
      float mnew = fmaxf(mrow[i], m2);
      float scale = __expf(mrow[i] - mnew);
      mrow[i] = mnew;
      float psum = 0.f;
      #pragma unroll
      for (int kn = 0; kn < 4; ++kn) { pv[kn][i] = __expf(pv[kn][i] - mnew); psum += pv[kn][i]; }
      #pragma unroll
      for (int off = 1; off < 16; off <<= 1) psum += __shfl_xor(psum, off, 64);
      lsum[i] = lsum[i]*scale + psum;
      #pragma unroll
      for (int dn = 0; dn < 4; ++dn) o[dn][i] *= scale;
    }

    #pragma unroll
    for (int kn = 0; kn < 4; ++kn)
      #pragma unroll
      for (int i = 0; i < 4; ++i) {
        int row = w*16 + g*4 + i;
        int col = kn*16 + lr;
        Ps[row*64 + (((col >> 3) ^ (row & 7)) * 8) + (col & 7)] = f2bf(pv[kn][i]);
      }

    #pragma unroll
    for (int kk2 = 0; kk2 < 2; ++kk2) {
      int prow = w*16 + lr;
      bf8 pa = *(const bf8*)&Ps[prow*64 + (((kk2*4+g) ^ (prow & 7)) * 8)];
      #pragma unroll
      for (int dn = 0; dn < 4; ++dn) {
        int vrow = dn*16 + lr;
        bf8 bv = *(const bf8*)&Vs[vrow*64 + (((kk2*4+g) ^ (vrow & 7)) * 8)];
        o[dn] = __builtin_amdgcn_mfma_f32_16x16x32_bf16(pa, bv, o[dn], 0,0,0);
      }
    }
    __syncthreads();
  }

  #pragma unroll
  for (int i = 0; i < 4; ++i) {
    float inv = 1.f / lsum[i];
    #pragma unroll
    for (int dn = 0; dn < 4; ++dn)
      ctx[(long)(b*768 + q0 + w*16 + g*4 + i)*512 + h*64 + dn*16 + lr] = f2bf(o[dn][i]*inv);
  }
}

// ------- single batched transpose + fp32->bf16: 7 weight matrices, 1 launch -------
struct TP {
  const float* src[7]; ushort* dst[7];
  int R[7], C[7]; int start[7]; int tilesX[7];
};
__global__ __launch_bounds__(256) void transpose_all(TP tp) {
  __shared__ float t[32][33];
  int blk = blockIdx.x;
  int m = 0;
  #pragma unroll
  for (int i = 1; i < 7; ++i) if (blk >= tp.start[i]) m = i;
  int rel = blk - tp.start[m];
  int bx = rel % tp.tilesX[m], by = rel / tp.tilesX[m];
  const float* src = tp.src[m];
  ushort* dst = tp.dst[m];
  int R = tp.R[m], C = tp.C[m];
  int r0 = bx*32, c0 = by*32;
  int tr = threadIdx.x >> 5, tc = threadIdx.x & 31;
  #pragma unroll
  for (int i = 0; i < 4; ++i)
    t[tr + i*8][tc] = src[(long)(r0 + tr + i*8)*C + c0 + tc];
  __syncthreads();
  #pragma unroll
  for (int i = 0; i < 4; ++i)
    dst[(long)(c0 + tr + i*8)*R + r0 + tc] = f2bf(t[tc][tr + i*8]);
}

// ---------------- LayerNorm (row=512) -> bf16 ----------------
__global__ __launch_bounds__(256) void ln_k(const float* x, const float* gam, const float* bet, ushort* out) {
  int row = blockIdx.x, tid = threadIdx.x;
  long base = (long)row*512;
  float v0 = x[base+tid], v1 = x[base+tid+256];
  float s = v0+v1, q = v0*v0 + v1*v1;
  #pragma unroll
  for (int off=32; off>=1; off>>=1){ s += __shfl_down(s,off,64); q += __shfl_down(q,off,64); }
  __shared__ float red[8];
  int lane=tid&63, wave=tid>>6;
  if (lane==0){ red[wave]=s; red[4+wave]=q; }
  __syncthreads();
  if (tid==0){ red[0]=red[0]+red[1]+red[2]+red[3]; red[4]=red[4]+red[5]+red[6]+red[7]; }
  __syncthreads();
  float mu = red[0]*(1.f/512.f);
  float var = red[4]*(1.f/512.f) - mu*mu;
  float rs = rsqrtf(var + 1e-5f);
  out[base+tid]     = f2bf((v0-mu)*rs*gam[tid]     + bet[tid]);
  out[base+tid+256] = f2bf((v1-mu)*rs*gam[tid+256] + bet[tid+256]);
}

// ---------------- residual + LayerNorm2 ----------------
__global__ __launch_bounds__(256) void resid_ln2_k(const float* x, const float* ao, const float* gc,
    const float* gatep, const float* gam, const float* bet, float* xmid, ushort* h2) {
  int row = blockIdx.x, tid = threadIdx.x;
  long base = (long)row*512;
  float gate = *gatep;
  float v0 = x[base+tid]     + ao[base+tid]     + gc[base+tid]*gate;
  float v1 = x[base+tid+256] + ao[base+tid+256] + gc[base+tid+256]*gate;
  xmid[base+tid] = v0; xmid[base+tid+256] = v1;
  float s = v0+v1, q = v0*v0 + v1*v1;
  #pragma unroll
  for (int off=32; off>=1; off>>=1){ s += __shfl_down(s,off,64); q += __shfl_down(q,off,64); }
  __shared__ float red[8];
  int lane=tid&63, wave=tid>>6;
  if (lane==0){ red[wave]=s; red[4+wave]=q; }
  __syncthreads();
  if (tid==0){ red[0]=red[0]+red[1]+red[2]+red[3]; red[4]=red[4]+red[5]+red[6]+red[7]; }
  __syncthreads();
  float mu = red[0]*(1.f/512.f);
  float var = red[4]*(1.f/512.f) - mu*mu;
  float rs = rsqrtf(var + 1e-5f);
  h2[base+tid]     = f2bf((v0-mu)*rs*gam[tid]     + bet[tid]);
  h2[base+tid+256] = f2bf((v1-mu)*rs*gam[tid+256] + bet[tid+256]);
}

// ------- fused single geom pass: adj (row-normalized) + 8-head score bias -------
__global__ __launch_bounds__(256) void adjbias_k(const float* __restrict__ geom,
    const int* __restrict__ mask, const float* __restrict__ Wg, const float* __restrict__ bg,
    ushort* __restrict__ adjb, ushort* __restrict__ biasb) {
  int bl = blockIdx.x;
  int b = bl / 768, l = bl - b*768;
  int tid = threadIdx.x;
  __shared__ float wgs[56];
  __shared__ float bgs[8];
  if (tid < 56) wgs[tid] = Wg[tid];
  if (tid < 8)  bgs[tid] = bg[tid];
  __syncthreads();
  float ml = (float)mask[bl];
  float e[3]; float ssum = 0.f;
  #pragma unroll
  for (int j = 0; j < 3; ++j) {
    int m = tid + j*256;
    const float* gp = &geom[((long)bl*768 + m)*7];
    float g0 = gp[0], g1 = gp[1], g2 = gp[2], g3 = gp[3], g4 = gp[4], g5 = gp[5], g6 = gp[6];
    float mm = (float)mask[b*768 + m];
    e[j] = __expf(-g0*0.2f) * mm;
    ssum += e[j];
    #pragma unroll
    for (int hh = 0; hh < 8; ++hh) {
      float bv = bgs[hh] + g0*wgs[hh] + g1*wgs[8+hh] + g2*wgs[16+hh] + g3*wgs[24+hh]
               + g4*wgs[32+hh] + g5*wgs[40+hh] + g6*wgs[48+hh];
      biasb[((long)(b*8+hh)*768 + l)*768 + m] = f2bf(mm != 0.f ? bv : -10000.f);
    }
  }
  #pragma unroll
  for (int off=32; off>=1; off>>=1) ssum += __shfl_down(ssum, off, 64);
  __shared__ float red[4];
  int lane = tid & 63, wave = tid >> 6;
  if (lane == 0) red[wave] = ssum;
  __syncthreads();
  if (tid == 0) red[0] = red[0]+red[1]+red[2]+red[3];
  __syncthreads();
  float inv = ml / (ml*red[0] + 1e-6f);
  #pragma unroll
  for (int j = 0; j < 3; ++j)
    adjb[(long)bl*768 + tid + j*256] = f2bf(e[j] * inv);
}

extern "C" void kernel_launch(void* const* d_in, const int* in_sizes, int n_in,
                              void* d_out, int out_size, void* d_ws, size_t ws_size,
                              hipStream_t stream) {
  const float* x    = (const float*)d_in[0];
  const float* geom = (const float*)d_in[1];
  const int*   mask = (const int*)d_in[2];
  const float* Wq   = (const float*)d_in[3];
  const float* bq   = (const float*)d_in[4];
  const float* Wk   = (const float*)d_in[5];
  const float* bk   = (const float*)d_in[6];
  const float* Wv   = (const float*)d_in[7];
  const float* bv   = (const float*)d_in[8];
  const float* Wo   = (const float*)d_in[9];
  const float* bo   = (const float*)d_in[10];
  const float* Wg   = (const float*)d_in[11];
  const float* bg   = (const float*)d_in[12];
  const float* Wgcn = (const float*)d_in[13];
  const float* bgcn = (const float*)d_in[14];
  const float* gate = (const float*)d_in[15];
  const float* W1   = (const float*)d_in[16];
  const float* b1   = (const float*)d_in[17];
  const float* W2   = (const float*)d_in[18];
  const float* b2   = (const float*)d_in[19];
  const float* ln1s = (const float*)d_in[20];
  const float* ln1b = (const float*)d_in[21];
  const float* ln2s = (const float*)d_in[22];
  const float* ln2b = (const float*)d_in[23];
  float* out = (float*)d_out;

  char* wp = (char*)d_ws;
  auto alloc = [&](size_t bytes)->char* { char* r = wp; wp += (bytes + 255) & ~(size_t)255; return r; };
  ushort* wqkvgT = (ushort*)alloc(2048*512*2);
  ushort* woT    = (ushort*)alloc(512*512*2);
  ushort* w1T    = (ushort*)alloc(4096*512*2);
  ushort* w2T    = (ushort*)alloc(512*2048*2);
  ushort* hbf    = (ushort*)alloc(3072*512*2);
  ushort* qbf    = (ushort*)alloc(3072*512*2);
  ushort* kbf    = (ushort*)alloc(3072*512*2);
  ushort* vt     = (ushort*)alloc((size_t)4*512*768*2);
  ushort* gt     = (ushort*)alloc((size_t)4*512*768*2);
  ushort* adjb   = (ushort*)alloc((size_t)4*768*768*2);
  ushort* biasb  = (ushort*)alloc((size_t)32*768*768*2);
  ushort* ctx    = (ushort*)alloc(3072*512*2);
  float*  aout   = (float*)alloc(3072*512*4);
  float*  gcnr   = (float*)alloc(3072*512*4);
  float*  xmid   = (float*)alloc(3072*512*4);
  ushort* h2bf   = (ushort*)alloc(3072*512*2);
  ushort* act    = biasb;   // reuse: bias dead after flash_k

  // one batched transpose launch for all 7 weight matrices
  TP tp;
  const float* srcs[7] = { Wq, Wk, Wv, Wgcn, Wo, W1, W2 };
  ushort* dsts[7] = { wqkvgT, wqkvgT + 512*512, wqkvgT + 2*512*512, wqkvgT + 3*512*512,
                      woT, w1T, w2T };
  int Rs[7] = { 512,512,512,512,512,512,2048 };
  int Cs[7] = { 512,512,512,512,512,4096,512 };
  int startAcc = 0;
  for (int i = 0; i < 7; ++i) {
    tp.src[i] = srcs[i]; tp.dst[i] = dsts[i]; tp.R[i] = Rs[i]; tp.C[i] = Cs[i];
    tp.tilesX[i] = Rs[i] / 32;
    tp.start[i] = startAcc;
    startAcc += (Rs[i]/32) * (Cs[i]/32);
  }
  transpose_all<<<startAcc, 256, 0, stream>>>(tp);

  ln_k<<<3072, 256, 0, stream>>>(x, ln1s, ln1b, hbf);
  adjbias_k<<<3072, 256, 0, stream>>>(geom, mask, Wg, bg, adjb, biasb);

  GP p{};
  // QKVG: h @ [Wq|Wk|Wv|Wgcn]  (M=3072,N=2048,K=512), grid 48x32
  p.A = hbf; p.lda = 512; p.aBatch = 0;
  p.Bt = wqkvgT; p.ldb = 512; p.bBatch = 0;
  p.K = 512;
  p.outb = qbf; p.o1 = kbf; p.o2 = vt; p.o3 = gt;
  p.bias0 = bq; p.bias1 = bk; p.bias2 = bv; p.bias3 = bgcn;
  gemm_k<EP_QKVG,false><<<dim3(48,32,1), 256, 0, stream>>>(p);

  // flash attention
  flash_k<<<dim3(12,32), 256, 0, stream>>>(qbf, kbf, vt, biasb, ctx);

  // GCN: adj @ g with gelu (M=768,N=512,K=768 per batch), grid 12x8x4
  p = GP{};
  p.A = adjb; p.lda = 768; p.aBatch = (long)768*768;
  p.Bt = gt; p.ldb = 768; p.bBatch = (long)512*768;
  p.K = 768;
  p.outf = gcnr;
  gemm_k<EP_GCN,false><<<dim3(12,8,4), 256, 0, stream>>>(p);

  // attn_out = ctx @ Wo + bo  (M=3072,N=512,K=512), grid 48x8
  p = GP{};
  p.A = ctx; p.lda = 512; p.aBatch = 0;
  p.Bt = woT; p.ldb = 512; p.bBatch = 0;
  p.K = 512;
  p.outf = aout; p.bias0 = bo;
  gemm_k<EP_ATTNOUT,false><<<dim3(48,8,1), 256, 0, stream>>>(p);

  resid_ln2_k<<<3072, 256, 0, stream>>>(x, aout, gcnr, gate, ln2s, ln2b, xmid, h2bf);

  // FFN1 dual: u,gate + GLU  (M=3072,N=2048 x2,K=512), grid 48x32
  p = GP{};
  p.A = h2bf; p.lda = 512; p.aBatch = 0;
  p.Bt = w1T; p.ldb = 512; p.bBatch = 0;
  p.Bt2 = w1T + (long)2048*512;
  p.K = 512;
  p.outb = act; p.bias0 = b1;
  gemm_k<EP_FF,true><<<dim3(48,32,1), 256, 0, stream>>>(p);

  // FFN2 + final residual  (M=3072,N=512,K=2048), grid 48x8
  p = GP{};
  p.A = act; p.lda = 2048; p.aBatch = 0;
  p.Bt = w2T; p.ldb = 2048; p.bBatch = 0;
  p.K = 2048;
  p.outf = out; p.bias0 = b2; p.addf = xmid;
  gemm_k<EP_FINAL,false><<<dim3(48,8,1), 256, 0, stream>>>(p);
}

// Round 11
// 289.099 us; speedup vs baseline: 1.3558x; 1.0042x over previous
//
#include <hip/hip_runtime.h>
#include <hip/hip_bf16.h>
#include <math.h>

typedef __attribute__((ext_vector_type(8))) short bf8;
typedef __attribute__((ext_vector_type(4))) float f4;

typedef const __attribute__((address_space(1))) void* gas_t;
typedef __attribute__((address_space(3))) void* las_t;

__device__ __forceinline__ ushort f2bf(float x){
  union { float f; unsigned u; } v; v.f = x;
  unsigned r = (v.u + 0x7fffu + ((v.u >> 16) & 1u)) >> 16;
  return (ushort)r;
}
__device__ __forceinline__ float bf2f(ushort b){
  union { unsigned u; float f; } v; v.u = ((unsigned)b) << 16;
  return v.f;
}

// ---- generic BMxBN tile, BK-step bf16 MFMA GEMM, global_load_lds(16B) staging ----
// LINEAR LDS dest (wave base + lane*16B); XOR swizzle folded into per-lane GLOBAL
// source column; reader uses same XOR. Tile sizes chosen per GEMM to keep >=384
// blocks (occupancy) while maximizing MFMA per staged byte.
struct GP {
  const ushort* A; long lda; long aBatch;
  const ushort* Bt; long ldb; long bBatch;
  const ushort* Bt2;
  int K;
  float* outf; ushort* outb;
  ushort* o1; ushort* o2; ushort* o3;
  const float* bias0; const float* bias1; const float* bias2; const float* bias3;
  const float* addf;
};

enum { EP_QKVG=0, EP_GCN, EP_ATTNOUT, EP_FF, EP_FINAL };

template<int EPI, bool DUAL, int BM, int BN, int BK>
__global__ __launch_bounds__(256)
void gemm_k(GP p) {
  constexpr int LPR = BK/8;          // lanes per row (16B chunks per row)
  constexpr int RPR = 2048/BK;       // rows per staging round (4KB per round)
  constexpr int AR  = BM/RPR;        // staging rounds for A
  constexpr int BR  = BN/RPR;        // staging rounds for B
  constexpr int WMW = (BN>=128) ? 2 : ((BM==128) ? 4 : 2);
  constexpr int WNW = 4/WMW;
  constexpr int WM = BM/WMW, WN = BN/WNW;
  constexpr int MF = WM/16, NF = WN/16;
  __shared__ __align__(16) ushort As[BM*BK];
  __shared__ __align__(16) ushort Bs[BN*BK];
  __shared__ __align__(16) ushort Bs2[DUAL ? BN*BK : 8];
  const int tid = threadIdx.x;
  const int lane = tid & 63, w = tid >> 6;
  const int wm = (WNW==1) ? w : (w >> 1);
  const int wn = (WNW==1) ? 0 : (w & 1);
  const int g = lane >> 4, lr = lane & 15;
  const int rl = lane / LPR, sc = lane % LPR;   // staging row-in-wave, col chunk
  const int bm = blockIdx.x, bn = blockIdx.y, z = blockIdx.z;

  const ushort* Ab  = p.A  + (long)z*p.aBatch + (long)bm*BM*p.lda;
  const ushort* Btb = p.Bt + (long)z*p.bBatch + (long)bn*BN*p.ldb;
  const ushort* Bt2b = DUAL ? (p.Bt2 + (long)bn*BN*p.ldb) : (const ushort*)nullptr;

  f4 acc[MF][NF] = {};
  f4 acc2[DUAL?MF:1][DUAL?NF:1] = {};

  for (int k0 = 0; k0 < p.K; k0 += BK) {
    #pragma unroll
    for (int i = 0; i < AR; ++i) {
      int row = i*RPR + w*(RPR/4) + rl;
      int scol = (sc ^ (row & (LPR-1))) << 3;
      __builtin_amdgcn_global_load_lds((gas_t)(Ab + (long)row*p.lda + k0 + scol),
                                       (las_t)&As[(i*RPR + w*(RPR/4))*BK], 16, 0, 0);
    }
    #pragma unroll
    for (int i = 0; i < BR; ++i) {
      int row = i*RPR + w*(RPR/4) + rl;
      int scol = (sc ^ (row & (LPR-1))) << 3;
      __builtin_amdgcn_global_load_lds((gas_t)(Btb + (long)row*p.ldb + k0 + scol),
                                       (las_t)&Bs[(i*RPR + w*(RPR/4))*BK], 16, 0, 0);
      if (DUAL)
        __builtin_amdgcn_global_load_lds((gas_t)(Bt2b + (long)row*p.ldb + k0 + scol),
                                         (las_t)&Bs2[(i*RPR + w*(RPR/4))*BK], 16, 0, 0);
    }
    __syncthreads();

    #pragma unroll
    for (int kw = 0; kw < BK/32; ++kw) {
      const int chunk = kw*4 + g;
      bf8 af[MF], bfr[NF], bf2[DUAL?NF:1];
      #pragma unroll
      for (int f = 0; f < MF; ++f) {
        int ar = wm*WM + f*16 + lr;
        af[f] = *(const bf8*)&As[ar*BK + ((chunk ^ (ar & (LPR-1))) << 3)];
      }
      #pragma unroll
      for (int f = 0; f < NF; ++f) {
        int br = wn*WN + f*16 + lr;
        bfr[f] = *(const bf8*)&Bs[br*BK + ((chunk ^ (br & (LPR-1))) << 3)];
        if (DUAL) bf2[f] = *(const bf8*)&Bs2[br*BK + ((chunk ^ (br & (LPR-1))) << 3)];
      }
      #pragma unroll
      for (int fm = 0; fm < MF; ++fm)
        #pragma unroll
        for (int fn = 0; fn < NF; ++fn) {
          acc[fm][fn] = __builtin_amdgcn_mfma_f32_16x16x32_bf16(af[fm], bfr[fn], acc[fm][fn], 0,0,0);
          if (DUAL) acc2[fm][fn] = __builtin_amdgcn_mfma_f32_16x16x32_bf16(af[fm], bf2[fn], acc2[fm][fn], 0,0,0);
        }
    }
    __syncthreads();
  }

  #pragma unroll
  for (int fm = 0; fm < MF; ++fm)
  #pragma unroll
  for (int fn = 0; fn < NF; ++fn)
  #pragma unroll
  for (int i = 0; i < 4; ++i) {
    int grow = bm*BM + wm*WM + fm*16 + g*4 + i;
    int gcol = bn*BN + wn*WN + fn*16 + lr;
    float v = acc[fm][fn][i];
    if constexpr (EPI == EP_QKVG) {
      int sec = gcol >> 9, cc = gcol & 511;
      const float* bp = sec==0 ? p.bias0 : sec==1 ? p.bias1 : sec==2 ? p.bias2 : p.bias3;
      v += bp[cc];
      if (sec == 0) v *= 0.125f;          // fold 1/sqrt(dk) into Q
      ushort bvv = f2bf(v);
      if (sec == 0)      p.outb[(long)grow*512 + cc] = bvv;
      else if (sec == 1) p.o1[(long)grow*512 + cc] = bvv;
      else {
        int b = grow / 768, l = grow - b*768;
        ushort* dst = (sec==2) ? p.o2 : p.o3;
        dst[((long)b*512 + cc)*768 + l] = bvv;
      }
    } else if constexpr (EPI == EP_GCN) {
      float ge = 0.5f * v * (1.f + erff(v * 0.70710678118f));
      p.outf[((long)z*768 + grow)*512 + gcol] = ge;
    } else if constexpr (EPI == EP_ATTNOUT) {
      p.outf[(long)grow*512 + gcol] = v + p.bias0[gcol];
    } else if constexpr (EPI == EP_FF) {
      float u = v + p.bias0[gcol];
      float gt = acc2[fm][fn][i] + p.bias0[2048 + gcol];
      float a = u / (1.f + expf(-gt));
      p.outb[(long)grow*2048 + gcol] = f2bf(a);
    } else if constexpr (EPI == EP_FINAL) {
      long idx = (long)grow*512 + gcol;
      p.outf[idx] = p.addf[idx] + v + p.bias0[gcol];
    }
  }
}

// -------- fused flash attention: scores(+bias) -> online softmax -> PV --------
__global__ __launch_bounds__(256) void flash_k(const ushort* __restrict__ qg,
    const ushort* __restrict__ kg, const ushort* __restrict__ vtg,
    const ushort* __restrict__ biasg, ushort* __restrict__ ctx) {
  __shared__ __align__(16) ushort Ks[64*64];
  __shared__ __align__(16) ushort Vs[64*64];
  __shared__ __align__(16) ushort Ps[64*64];
  const int tid = threadIdx.x;
  const int lane = tid & 63, w = tid >> 6;
  const int g = lane >> 4, lr = lane & 15;
  const int qt = blockIdx.x, bh = blockIdx.y;
  const int b = bh >> 3, h = bh & 7;
  const int q0 = qt*64;

  bf8 aq[2];
  #pragma unroll
  for (int kk = 0; kk < 2; ++kk)
    aq[kk] = *(const bf8*)&qg[(long)(b*768 + q0 + w*16 + lr)*512 + h*64 + kk*32 + g*8];

  f4 o[4] = {};
  float mrow[4], lsum[4];
  #pragma unroll
  for (int i = 0; i < 4; ++i) { mrow[i] = -1e30f; lsum[i] = 0.f; }

  const int srow = tid >> 3, sc = tid & 7;

  for (int kt = 0; kt < 12; ++kt) {
    const int kbase = kt*64;
    #pragma unroll
    for (int ps = 0; ps < 2; ++ps) {
      int r = srow + ps*32;
      int sw = ((sc ^ (r & 7)) * 8);
      *(uint4*)&Ks[r*64 + sw] = *(const uint4*)&kg[(long)(b*768 + kbase + r)*512 + h*64 + sc*8];
      *(uint4*)&Vs[r*64 + sw] = *(const uint4*)&vtg[((long)b*512 + h*64 + r)*768 + kbase + sc*8];
    }
    __syncthreads();

    f4 s[4] = {};
    #pragma unroll
    for (int kn = 0; kn < 4; ++kn) {
      #pragma unroll
      for (int kk = 0; kk < 2; ++kk) {
        int row = kn*16 + lr;
        bf8 bk = *(const bf8*)&Ks[row*64 + (((kk*4+g) ^ (row & 7)) * 8)];
        s[kn] = __builtin_amdgcn_mfma_f32_16x16x32_bf16(aq[kk], bk, s[kn], 0,0,0);
      }
    }

    float pv[4][4];
    #pragma unroll
    for (int kn = 0; kn < 4; ++kn)
      #pragma unroll
      for (int i = 0; i < 4; ++i) {
        float bv = bf2f(biasg[((long)bh*768 + q0 + w*16 + g*4 + i)*768 + kbase + kn*16 + lr]);
        pv[kn][i] = s[kn][i] + bv;   // Q pre-scaled by 0.125
      }

    #pragma unroll
    for (int i = 0; i < 4; ++i) {
      float m2 = fmaxf(fmaxf(pv[0][i], pv[1][i]), fmaxf(pv[2][i], pv[3][i]));
      #pragma unroll
      for (int off = 1; off < 16; off <<= 1) m2 = fmaxf(m2, __shfl_xor(m2, off, 64));
      float mnew = fmaxf(mrow[i], m2);
      float scale = __expf(mrow[i] - mnew);
      mrow[i] = mnew;
      float psum = 0.f;
      #pragma unroll
      for (int kn = 0; kn < 4; ++kn) { pv[kn][i] = __expf(pv[kn][i] - mnew); psum += pv[kn][i]; }
      #pragma unroll
      for (int off = 1; off < 16; off <<= 1) psum += __shfl_xor(psum, off, 64);
      lsum[i] = lsum[i]*scale + psum;
      #pragma unroll
      for (int dn = 0; dn < 4; ++dn) o[dn][i] *= scale;
    }

    #pragma unroll
    for (int kn = 0; kn < 4; ++kn)
      #pragma unroll
      for (int i = 0; i < 4; ++i) {
        int row = w*16 + g*4 + i;
        int col = kn*16 + lr;
        Ps[row*64 + (((col >> 3) ^ (row & 7)) * 8) + (col & 7)] = f2bf(pv[kn][i]);
      }

    #pragma unroll
    for (int kk2 = 0; kk2 < 2; ++kk2) {
      int prow = w*16 + lr;
      bf8 pa = *(const bf8*)&Ps[prow*64 + (((kk2*4+g) ^ (prow & 7)) * 8)];
      #pragma unroll
      for (int dn = 0; dn < 4; ++dn) {
        int vrow = dn*16 + lr;
        bf8 bv = *(const bf8*)&Vs[vrow*64 + (((kk2*4+g) ^ (vrow & 7)) * 8)];
        o[dn] = __builtin_amdgcn_mfma_f32_16x16x32_bf16(pa, bv, o[dn], 0,0,0);
      }
    }
    __syncthreads();
  }

  #pragma unroll
  for (int i = 0; i < 4; ++i) {
    float inv = 1.f / lsum[i];
    #pragma unroll
    for (int dn = 0; dn < 4; ++dn)
      ctx[(long)(b*768 + q0 + w*16 + g*4 + i)*512 + h*64 + dn*16 + lr] = f2bf(o[dn][i]*inv);
  }
}

// ------- single batched transpose + fp32->bf16: 7 weight matrices, 1 launch -------
struct TP {
  const float* src[7]; ushort* dst[7];
  int R[7], C[7]; int start[7]; int tilesX[7];
};
__global__ __launch_bounds__(256) void transpose_all(TP tp) {
  __shared__ float t[32][33];
  int blk = blockIdx.x;
  int m = 0;
  #pragma unroll
  for (int i = 1; i < 7; ++i) if (blk >= tp.start[i]) m = i;
  int rel = blk - tp.start[m];
  int bx = rel % tp.tilesX[m], by = rel / tp.tilesX[m];
  const float* src = tp.src[m];
  ushort* dst = tp.dst[m];
  int R = tp.R[m], C = tp.C[m];
  int r0 = bx*32, c0 = by*32;
  int tr = threadIdx.x >> 5, tc = threadIdx.x & 31;
  #pragma unroll
  for (int i = 0; i < 4; ++i)
    t[tr + i*8][tc] = src[(long)(r0 + tr + i*8)*C + c0 + tc];
  __syncthreads();
  #pragma unroll
  for (int i = 0; i < 4; ++i)
    dst[(long)(c0 + tr + i*8)*R + r0 + tc] = f2bf(t[tc][tr + i*8]);
}

// ---------------- LayerNorm (row=512) -> bf16 ----------------
__global__ __launch_bounds__(256) void ln_k(const float* x, const float* gam, const float* bet, ushort* out) {
  int row = blockIdx.x, tid = threadIdx.x;
  long base = (long)row*512;
  float v0 = x[base+tid], v1 = x[base+tid+256];
  float s = v0+v1, q = v0*v0 + v1*v1;
  #pragma unroll
  for (int off=32; off>=1; off>>=1){ s += __shfl_down(s,off,64); q += __shfl_down(q,off,64); }
  __shared__ float red[8];
  int lane=tid&63, wave=tid>>6;
  if (lane==0){ red[wave]=s; red[4+wave]=q; }
  __syncthreads();
  if (tid==0){ red[0]=red[0]+red[1]+red[2]+red[3]; red[4]=red[4]+red[5]+red[6]+red[7]; }
  __syncthreads();
  float mu = red[0]*(1.f/512.f);
  float var = red[4]*(1.f/512.f) - mu*mu;
  float rs = rsqrtf(var + 1e-5f);
  out[base+tid]     = f2bf((v0-mu)*rs*gam[tid]     + bet[tid]);
  out[base+tid+256] = f2bf((v1-mu)*rs*gam[tid+256] + bet[tid+256]);
}

// ---------------- residual + LayerNorm2 ----------------
__global__ __launch_bounds__(256) void resid_ln2_k(const float* x, const float* ao, const float* gc,
    const float* gatep, const float* gam, const float* bet, float* xmid, ushort* h2) {
  int row = blockIdx.x, tid = threadIdx.x;
  long base = (long)row*512;
  float gate = *gatep;
  float v0 = x[base+tid]     + ao[base+tid]     + gc[base+tid]*gate;
  float v1 = x[base+tid+256] + ao[base+tid+256] + gc[base+tid+256]*gate;
  xmid[base+tid] = v0; xmid[base+tid+256] = v1;
  float s = v0+v1, q = v0*v0 + v1*v1;
  #pragma unroll
  for (int off=32; off>=1; off>>=1){ s += __shfl_down(s,off,64); q += __shfl_down(q,off,64); }
  __shared__ float red[8];
  int lane=tid&63, wave=tid>>6;
  if (lane==0){ red[wave]=s; red[4+wave]=q; }
  __syncthreads();
  if (tid==0){ red[0]=red[0]+red[1]+red[2]+red[3]; red[4]=red[4]+red[5]+red[6]+red[7]; }
  __syncthreads();
  float mu = red[0]*(1.f/512.f);
  float var = red[4]*(1.f/512.f) - mu*mu;
  float rs = rsqrtf(var + 1e-5f);
  h2[base+tid]     = f2bf((v0-mu)*rs*gam[tid]     + bet[tid]);
  h2[base+tid+256] = f2bf((v1-mu)*rs*gam[tid+256] + bet[tid+256]);
}

// ------- fused single geom pass: adj (row-normalized) + 8-head score bias -------
__global__ __launch_bounds__(256) void adjbias_k(const float* __restrict__ geom,
    const int* __restrict__ mask, const float* __restrict__ Wg, const float* __restrict__ bg,
    ushort* __restrict__ adjb, ushort* __restrict__ biasb) {
  int bl = blockIdx.x;
  int b = bl / 768, l = bl - b*768;
  int tid = threadIdx.x;
  __shared__ float wgs[56];
  __shared__ float bgs[8];
  if (tid < 56) wgs[tid] = Wg[tid];
  if (tid < 8)  bgs[tid] = bg[tid];
  __syncthreads();
  float ml = (float)mask[bl];
  float e[3]; float ssum = 0.f;
  #pragma unroll
  for (int j = 0; j < 3; ++j) {
    int m = tid + j*256;
    const float* gp = &geom[((long)bl*768 + m)*7];
    float g0 = gp[0], g1 = gp[1], g2 = gp[2], g3 = gp[3], g4 = gp[4], g5 = gp[5], g6 = gp[6];
    float mm = (float)mask[b*768 + m];
    e[j] = __expf(-g0*0.2f) * mm;
    ssum += e[j];
    #pragma unroll
    for (int hh = 0; hh < 8; ++hh) {
      float bv = bgs[hh] + g0*wgs[hh] + g1*wgs[8+hh] + g2*wgs[16+hh] + g3*wgs[24+hh]
               + g4*wgs[32+hh] + g5*wgs[40+hh] + g6*wgs[48+hh];
      biasb[((long)(b*8+hh)*768 + l)*768 + m] = f2bf(mm != 0.f ? bv : -10000.f);
    }
  }
  #pragma unroll
  for (int off=32; off>=1; off>>=1) ssum += __shfl_down(ssum, off, 64);
  __shared__ float red[4];
  int lane = tid & 63, wave = tid >> 6;
  if (lane == 0) red[wave] = ssum;
  __syncthreads();
  if (tid == 0) red[0] = red[0]+red[1]+red[2]+red[3];
  __syncthreads();
  float inv = ml / (ml*red[0] + 1e-6f);
  #pragma unroll
  for (int j = 0; j < 3; ++j)
    adjb[(long)bl*768 + tid + j*256] = f2bf(e[j] * inv);
}

extern "C" void kernel_launch(void* const* d_in, const int* in_sizes, int n_in,
                              void* d_out, int out_size, void* d_ws, size_t ws_size,
                              hipStream_t stream) {
  const float* x    = (const float*)d_in[0];
  const float* geom = (const float*)d_in[1];
  const int*   mask = (const int*)d_in[2];
  const float* Wq   = (const float*)d_in[3];
  const float* bq   = (const float*)d_in[4];
  const float* Wk   = (const float*)d_in[5];
  const float* bk   = (const float*)d_in[6];
  const float* Wv   = (const float*)d_in[7];
  const float* bv   = (const float*)d_in[8];
  const float* Wo   = (const float*)d_in[9];
  const float* bo   = (const float*)d_in[10];
  const float* Wg   = (const float*)d_in[11];
  const float* bg   = (const float*)d_in[12];
  const float* Wgcn = (const float*)d_in[13];
  const float* bgcn = (const float*)d_in[14];
  const float* gate = (const float*)d_in[15];
  const float* W1   = (const float*)d_in[16];
  const float* b1   = (const float*)d_in[17];
  const float* W2   = (const float*)d_in[18];
  const float* b2   = (const float*)d_in[19];
  const float* ln1s = (const float*)d_in[20];
  const float* ln1b = (const float*)d_in[21];
  const float* ln2s = (const float*)d_in[22];
  const float* ln2b = (const float*)d_in[23];
  float* out = (float*)d_out;

  char* wp = (char*)d_ws;
  auto alloc = [&](size_t bytes)->char* { char* r = wp; wp += (bytes + 255) & ~(size_t)255; return r; };
  ushort* wqkvgT = (ushort*)alloc(2048*512*2);
  ushort* woT    = (ushort*)alloc(512*512*2);
  ushort* w1T    = (ushort*)alloc(4096*512*2);
  ushort* w2T    = (ushort*)alloc(512*2048*2);
  ushort* hbf    = (ushort*)alloc(3072*512*2);
  ushort* qbf    = (ushort*)alloc(3072*512*2);
  ushort* kbf    = (ushort*)alloc(3072*512*2);
  ushort* vt     = (ushort*)alloc((size_t)4*512*768*2);
  ushort* gt     = (ushort*)alloc((size_t)4*512*768*2);
  ushort* adjb   = (ushort*)alloc((size_t)4*768*768*2);
  ushort* biasb  = (ushort*)alloc((size_t)32*768*768*2);
  ushort* ctx    = (ushort*)alloc(3072*512*2);
  float*  aout   = (float*)alloc(3072*512*4);
  float*  gcnr   = (float*)alloc(3072*512*4);
  float*  xmid   = (float*)alloc(3072*512*4);
  ushort* h2bf   = (ushort*)alloc(3072*512*2);
  ushort* act    = biasb;   // reuse: bias dead after flash_k

  // one batched transpose launch for all 7 weight matrices
  TP tp;
  const float* srcs[7] = { Wq, Wk, Wv, Wgcn, Wo, W1, W2 };
  ushort* dsts[7] = { wqkvgT, wqkvgT + 512*512, wqkvgT + 2*512*512, wqkvgT + 3*512*512,
                      woT, w1T, w2T };
  int Rs[7] = { 512,512,512,512,512,512,2048 };
  int Cs[7] = { 512,512,512,512,512,4096,512 };
  int startAcc = 0;
  for (int i = 0; i < 7; ++i) {
    tp.src[i] = srcs[i]; tp.dst[i] = dsts[i]; tp.R[i] = Rs[i]; tp.C[i] = Cs[i];
    tp.tilesX[i] = Rs[i] / 32;
    tp.start[i] = startAcc;
    startAcc += (Rs[i]/32) * (Cs[i]/32);
  }
  transpose_all<<<startAcc, 256, 0, stream>>>(tp);

  ln_k<<<3072, 256, 0, stream>>>(x, ln1s, ln1b, hbf);
  adjbias_k<<<3072, 256, 0, stream>>>(geom, mask, Wg, bg, adjb, biasb);

  GP p{};
  // QKVG: h @ [Wq|Wk|Wv|Wgcn]  (M=3072,N=2048,K=512) -> 128x128 tile, grid 24x16
  p.A = hbf; p.lda = 512; p.aBatch = 0;
  p.Bt = wqkvgT; p.ldb = 512; p.bBatch = 0;
  p.K = 512;
  p.outb = qbf; p.o1 = kbf; p.o2 = vt; p.o3 = gt;
  p.bias0 = bq; p.bias1 = bk; p.bias2 = bv; p.bias3 = bgcn;
  gemm_k<EP_QKVG,false,128,128,64><<<dim3(24,16,1), 256, 0, stream>>>(p);

  // flash attention
  flash_k<<<dim3(12,32), 256, 0, stream>>>(qbf, kbf, vt, biasb, ctx);

  // GCN: adj @ g with gelu (M=768,N=512,K=768 per batch) -> 64x64 BK128, grid 12x8x4
  p = GP{};
  p.A = adjb; p.lda = 768; p.aBatch = (long)768*768;
  p.Bt = gt; p.ldb = 768; p.bBatch = (long)512*768;
  p.K = 768;
  p.outf = gcnr;
  gemm_k<EP_GCN,false,64,64,128><<<dim3(12,8,4), 256, 0, stream>>>(p);

  // attn_out = ctx @ Wo + bo  (M=3072,N=512,K=512) -> 64x64 BK128, grid 48x8
  p = GP{};
  p.A = ctx; p.lda = 512; p.aBatch = 0;
  p.Bt = woT; p.ldb = 512; p.bBatch = 0;
  p.K = 512;
  p.outf = aout; p.bias0 = bo;
  gemm_k<EP_ATTNOUT,false,64,64,128><<<dim3(48,8,1), 256, 0, stream>>>(p);

  resid_ln2_k<<<3072, 256, 0, stream>>>(x, aout, gcnr, gate, ln2s, ln2b, xmid, h2bf);

  // FFN1 dual: u,gate + GLU  (M=3072,N=2048 x2,K=512) -> 128x64 dual, grid 24x32
  p = GP{};
  p.A = h2bf; p.lda = 512; p.aBatch = 0;
  p.Bt = w1T; p.ldb = 512; p.bBatch = 0;
  p.Bt2 = w1T + (long)2048*512;
  p.K = 512;
  p.outb = act; p.bias0 = b1;
  gemm_k<EP_FF,true,128,64,64><<<dim3(24,32,1), 256, 0, stream>>>(p);

  // FFN2 + final residual  (M=3072,N=512,K=2048) -> 64x64 BK128, grid 48x8
  p = GP{};
  p.A = act; p.lda = 2048; p.aBatch = 0;
  p.Bt = w2T; p.ldb = 2048; p.bBatch = 0;
  p.K = 2048;
  p.outf = out; p.bias0 = b2; p.addf = xmid;
  gemm_k<EP_FINAL,false,64,64,128><<<dim3(48,8,1), 256, 0, stream>>>(p);
}